// Round 4
// baseline (4793.445 us; speedup 1.0000x reference)
//
#include <hip/hip_runtime.h>
#include <hip/hip_bf16.h>

// ---------------- problem constants ----------------
#define EMBN   512
#define HIDN   1024
#define OUTN   512
#define BBN    64
#define SSN    256
#define NBLK   256          // persistent blocks; block j owns 4 h-dims x 4 gates = 16 preact cols
#define PSTR   20           // preact LDS row stride (floats)

typedef __attribute__((ext_vector_type(8))) short bf16x8;
typedef __attribute__((ext_vector_type(4))) float f32x4;
typedef __attribute__((ext_vector_type(4))) unsigned int u32x4;
typedef unsigned short us;
typedef unsigned long long ull;

static __device__ __forceinline__ us f2bf(float x) {
  unsigned int u = __float_as_uint(x);
  unsigned int r = (u + 0x7fffu + ((u >> 16) & 1u)) >> 16;   // RNE
  return (us)r;
}
static __device__ __forceinline__ float bf2f(us u) {
  unsigned int v = ((unsigned int)u) << 16;
  return __uint_as_float(v);
}

// ---------------- weight prepack: [j(256)][kt(48)][lane(64)][8] ----------------
// block j owns preact cols p = 16j+q, q in [0,16): gate g=q>>2, r=q&3, hd=4j+r
__global__ void pack_w(const float* __restrict__ wxi, const float* __restrict__ wxf,
                       const float* __restrict__ wxo, const float* __restrict__ wxc,
                       const float* __restrict__ whi, const float* __restrict__ whf,
                       const float* __restrict__ who, const float* __restrict__ whc,
                       us* __restrict__ Whip, us* __restrict__ Wlop) {
  int idx = blockIdx.x * 256 + threadIdx.x;       // 256*48*64 = 786432
  int lane = idx & 63;
  int kt   = (idx >> 6) % 48;
  int j    = idx / (48 * 64);
  int q = lane & 15, g = q >> 2, r = q & 3;
  int hd = 4 * j + r;
  int kb = kt * 32 + ((lane >> 4) << 3);
  const float* wx = (g == 0) ? wxi : (g == 1) ? wxf : (g == 2) ? wxo : wxc;
  const float* wh = (g == 0) ? whi : (g == 1) ? whf : (g == 2) ? who : whc;
  long obase = (long)idx * 8;
  #pragma unroll
  for (int jj = 0; jj < 8; ++jj) {
    int k = kb + jj;
    float v = (k < EMBN) ? wx[(long)k * HIDN + hd] : wh[(long)(k - EMBN) * HIDN + hd];
    us hi = f2bf(v);
    us lo = f2bf(v - bf2f(hi));
    Whip[obase + jj] = hi;
    Wlop[obase + jj] = lo;
  }
}

// ---------------- embedding gather + hi/lo split: X[t][b][k] ----------------
__global__ void pack_x(const int* __restrict__ tokens, const float* __restrict__ emb,
                       us* __restrict__ Xhi, us* __restrict__ Xlo) {
  int idx = blockIdx.x * 256 + threadIdx.x;       // 256*64*512 = 8388608
  int k = idx & 511;
  int b = (idx >> 9) & 63;
  int t = idx >> 15;
  int tok = tokens[b * SSN + t];
  float v = emb[(long)tok * EMBN + k];
  us hi = f2bf(v);
  Xhi[idx] = hi;
  Xlo[idx] = f2bf(v - bf2f(hi));
}

// chunk = 4 kt (4 hi + 4 lo frags = 8 bf16x8 = 32 VGPR)
#define XISS(A, c) { _Pragma("unroll") for (int q = 0; q < 4; ++q) { \
      A[2*q]   = *(const bf16x8*)(xh + (((c)*4 + q) << 5)); \
      A[2*q+1] = *(const bf16x8*)(xl + (((c)*4 + q) << 5)); } }
#define XCON(A, c) { _Pragma("unroll") for (int q = 0; q < 4; ++q) { \
      const int kt = (c)*4 + q; \
      bf16x8 w0 = *(const bf16x8*)(WHi + (kt << 9) + (lane << 3)); \
      bf16x8 w1 = *(const bf16x8*)(WLo + (kt << 9) + (lane << 3)); \
      accA = __builtin_amdgcn_mfma_f32_16x16x32_bf16(w0, A[2*q],   accA, 0, 0, 0); \
      accB = __builtin_amdgcn_mfma_f32_16x16x32_bf16(w0, A[2*q+1], accB, 0, 0, 0); \
      accC = __builtin_amdgcn_mfma_f32_16x16x32_bf16(w1, A[2*q],   accC, 0, 0, 0); } }

// H load with sentinel capture: each 16B quad-pair checked via even u32s
// (producer stores are 8B-atomic; even u32 == 0xFFFFFFFF <=> unit still sentinel;
//  genuine data never matches: two bf16 NaNs can't come out of f2bf(finite)).
#define HLD(A, S, c) { _Pragma("unroll") for (int q = 0; q < 4; ++q) { \
      const int ct = (c)*4 + q; \
      u32x4 rh = *(const u32x4*)(hh + (ct << 5)); \
      u32x4 rl = *(const u32x4*)(hl + (ct << 5)); \
      A[2*q]   = *(bf16x8*)&rh; \
      A[2*q+1] = *(bf16x8*)&rl; \
      unsigned int m0 = rh.x > rh.z ? rh.x : rh.z; \
      unsigned int m1 = rl.x > rl.z ? rl.x : rl.z; \
      S[q] = m0 > m1 ? m0 : m1; } }
// retry path: uncached (LLC) reload of the whole 4-chunk set until no sentinel
#define HRLD(A, S, c) { _Pragma("unroll") for (int q = 0; q < 4; ++q) { \
      const int ct = (c)*4 + q; \
      u32x4 rh, rl; \
      asm volatile("global_load_dwordx4 %0, %2, off sc0 sc1\n\t" \
                   "global_load_dwordx4 %1, %3, off sc0 sc1\n\t" \
                   "s_waitcnt vmcnt(0)" \
                   : "=&v"(rh), "=&v"(rl) \
                   : "v"(hh + (ct << 5)), "v"(hl + (ct << 5)) : "memory"); \
      A[2*q]   = *(bf16x8*)&rh; \
      A[2*q+1] = *(bf16x8*)&rl; \
      unsigned int m0 = rh.x > rh.z ? rh.x : rh.z; \
      unsigned int m1 = rl.x > rl.z ? rl.x : rl.z; \
      S[q] = m0 > m1 ? m0 : m1; } }
#define HCHK(A, S, c) { \
      unsigned int m01 = S[0] > S[1] ? S[0] : S[1]; \
      unsigned int m23 = S[2] > S[3] ? S[2] : S[3]; \
      unsigned int mm  = m01 > m23 ? m01 : m23; \
      while (__builtin_expect(__any(mm == 0xffffffffu), 0)) { \
        __builtin_amdgcn_s_sleep(1); \
        HRLD(A, S, c) \
        m01 = S[0] > S[1] ? S[0] : S[1]; \
        m23 = S[2] > S[3] ? S[2] : S[3]; \
        mm  = m01 > m23 ? m01 : m23; } }
#define HCON(A, c) { _Pragma("unroll") for (int q = 0; q < 4; ++q) { \
      const int kt = 16 + (c)*4 + q; \
      bf16x8 w0 = *(const bf16x8*)(WHi + (kt << 9) + (lane << 3)); \
      bf16x8 w1 = *(const bf16x8*)(WLo + (kt << 9) + (lane << 3)); \
      accA = __builtin_amdgcn_mfma_f32_16x16x32_bf16(w0, A[2*q],   accA, 0, 0, 0); \
      accB = __builtin_amdgcn_mfma_f32_16x16x32_bf16(w0, A[2*q+1], accB, 0, 0, 0); \
      accC = __builtin_amdgcn_mfma_f32_16x16x32_bf16(w1, A[2*q],   accC, 0, 0, 0); } }

// ---------------- persistent LSTM recurrence ----------------
// 256 blocks x 256 threads (4 waves, one per SIMD). Wave wv = batches [16wv,16wv+16).
// NO flags, NO acks: the H ring is pre-filled with 0xFF sentinel; consumers poll
// the DATA (cached loads + sentinel check; rare sc0sc1 retry). Producer just
// stores and moves on. Plane wv <-> plane wv only (rows partition by wave).
// K==256: every slot written once -> no reuse hazards, no fences.
// K<256 : producer re-sentinels its slice of slot t+2 (acked before data store),
//         plus an agent acquire-fence at ring wrap to drop stale L1/L2 lines.
__launch_bounds__(256, 1)
__global__ void lstm_persist(const us* __restrict__ Whip, const us* __restrict__ Wlop,
                             const us* __restrict__ Xhi, const us* __restrict__ Xlo,
                             us* Hhi, us* Hlo, float* hfin,
                             const float* __restrict__ biP, const float* __restrict__ bfP,
                             const float* __restrict__ boP, const float* __restrict__ bcP,
                             int K) {
  extern __shared__ char smem[];
  us* WHi = (us*)smem;                         // 24576 shorts
  us* WLo = WHi + 24576;                       // 24576 shorts
  float* preact = (float*)(smem + 98304);      // [64][PSTR], rows partition by wave

  const int j = blockIdx.x, tid = threadIdx.x;
  const int wv = tid >> 6, lane = tid & 63;
  const int Km = K - 1;
  const bool SENT = (K != 256);

  // one-time: W slices -> LDS (fragment layout identical, straight copy)
  {
    const uint4* shi = (const uint4*)(Whip + (long)j * 24576);
    const uint4* slo = (const uint4*)(Wlop + (long)j * 24576);
    uint4* dhi = (uint4*)WHi;
    uint4* dlo = (uint4*)WLo;
    for (int i = tid; i < 3072; i += 256) { dhi[i] = shi[i]; dlo[i] = slo[i]; }
  }
  // gate mapping: thread -> (b = tid>>2, r = tid&3); c-state in register.
  const int gb = tid >> 2, gr = tid & 3;
  const float bi_r = biP[4 * j + gr], bf_r = bfP[4 * j + gr];
  const float bo_r = boP[4 * j + gr], bc_r = bcP[4 * j + gr];
  float c_reg = 0.f;

  const int mrow = (wv << 4) + (lane & 15);    // batch row (MFMA N-dim)
  const int kj = (lane >> 4) << 3;
  const int p0 = (lane >> 4) << 2;
  __syncthreads();                             // W in LDS ready (only barrier)

  f32x4 accA = {0.f, 0.f, 0.f, 0.f};
  f32x4 accB = {0.f, 0.f, 0.f, 0.f};
  f32x4 accC = {0.f, 0.f, 0.f, 0.f};

  // ---- prologue: acc = X(0) contribution ----
  {
    const us* xh = Xhi + (mrow << 9) + kj;
    const us* xl = Xlo + (mrow << 9) + kj;
    bf16x8 XA[8], XB[8];
    XISS(XA, 0) XISS(XB, 1)
    __builtin_amdgcn_sched_barrier(0);
    XCON(XA, 0) XISS(XA, 2)
    __builtin_amdgcn_sched_barrier(0);
    XCON(XB, 1) XISS(XB, 3)
    __builtin_amdgcn_sched_barrier(0);
    XCON(XA, 2) XCON(XB, 3)
  }

  #pragma unroll 1
  for (int t = 0; t < SSN; ++t) {
    if (t > 0) {
      if (SENT && (t & Km) == 0)
        __builtin_amdgcn_fence(__ATOMIC_ACQUIRE, "agent");  // ring wrap: drop stale lines

      // ---- H part: data-sentinel-synced loads + 4-deep load/MFMA pipeline ----
      const int cur = t & Km;
      const us* hh = Hhi + (((long)cur * BBN + mrow) << 10) + kj;
      const us* hl = Hlo + (((long)cur * BBN + mrow) << 10) + kj;
      bf16x8 HA[8], HB[8], HC[8], HD[8];
      unsigned int SA[4], SB_[4], SC[4], SD[4];
      HLD(HA, SA, 0) HLD(HB, SB_, 1) HLD(HC, SC, 2) HLD(HD, SD, 3)
      __builtin_amdgcn_sched_barrier(0);
      HCHK(HA, SA, 0)  HCON(HA, 0) HLD(HA, SA, 4)
      __builtin_amdgcn_sched_barrier(0);
      HCHK(HB, SB_, 1) HCON(HB, 1) HLD(HB, SB_, 5)
      __builtin_amdgcn_sched_barrier(0);
      HCHK(HC, SC, 2)  HCON(HC, 2) HLD(HC, SC, 6)
      __builtin_amdgcn_sched_barrier(0);
      HCHK(HD, SD, 3)  HCON(HD, 3) HLD(HD, SD, 7)
      __builtin_amdgcn_sched_barrier(0);
      HCHK(HA, SA, 4)  HCON(HA, 4)
      HCHK(HB, SB_, 5) HCON(HB, 5)
      HCHK(HC, SC, 6)  HCON(HC, 6)
      HCHK(HD, SD, 7)  HCON(HD, 7)

      // small-ring: re-sentinel own slice of slot t+2 before it can be re-read
      if (SENT && t + 2 >= K && t + 2 < SSN && gr == 0) {
        const long snt = (long)((t + 2) & Km);
        __hip_atomic_store((ull*)(Hhi + ((snt * BBN + gb) << 10) + 4 * j), ~0ull,
                           __ATOMIC_RELAXED, __HIP_MEMORY_SCOPE_AGENT);
        __hip_atomic_store((ull*)(Hlo + ((snt * BBN + gb) << 10) + 4 * j), ~0ull,
                           __ATOMIC_RELAXED, __HIP_MEMORY_SCOPE_AGENT);
      }
    }

    // ---- preact: lane holds D[p0+rg][mrow]; 16B LDS store (intra-wave rows) ----
    {
      f32x4 acc = accA + accB;
      acc = acc + accC;
      *(f32x4*)(preact + mrow * PSTR + p0) = acc;
    }
    // no barrier: producer lanes and consumer threads are the SAME wave.

    // ---- gates: one (b,r) per thread ----
    {
      float pi = preact[gb * PSTR + gr]      + bi_r;
      float pf = preact[gb * PSTR + 4 + gr]  + bf_r;
      float po = preact[gb * PSTR + 8 + gr]  + bo_r;
      float pc = preact[gb * PSTR + 12 + gr] + bc_r;
      float vi = 1.f / (1.f + expf(-pi));
      float vf = 1.f / (1.f + expf(-pf));
      float vo = 1.f / (1.f + expf(-po));
      float vc = tanhf(pc);
      c_reg = vf * c_reg + vi * vc;
      float h = vo * tanhf(c_reg);

      if (t == SSN - 1) {
        hfin[(gb << 10) + 4 * j + gr] = h;     // last step: only the final h matters
      } else {
        us hh_ = f2bf(h);
        us hl_ = f2bf(h - bf2f(hh_));
        // pack (hi,lo) of the 4 dims of this lane-group into two 8B quads
        unsigned int hpair = (unsigned int)hh_ | ((unsigned int)hl_ << 16);
        const int base = lane & ~3;
        unsigned int g0 = (unsigned int)__shfl((int)hpair, base);
        unsigned int g1 = (unsigned int)__shfl((int)hpair, base + 1);
        unsigned int g2 = (unsigned int)__shfl((int)hpair, base + 2);
        unsigned int g3 = (unsigned int)__shfl((int)hpair, base + 3);
        unsigned int hi01 = (g0 & 0xffffu) | (g1 << 16);
        unsigned int hi23 = (g2 & 0xffffu) | (g3 << 16);
        unsigned int lo01 = (g0 >> 16)     | (g1 & 0xffff0000u);
        unsigned int lo23 = (g2 >> 16)     | (g3 & 0xffff0000u);
        ull hiq = ((ull)hi23 << 32) | (ull)hi01;
        ull loq = ((ull)lo23 << 32) | (ull)lo01;

        // small-ring only: sentinel(t+2) must be in LLC before data(t+1) lands
        if (SENT) asm volatile("s_waitcnt vmcnt(0)" ::: "memory");

        const long nxt = (long)((t + 1) & Km);
        if (gr == 0) {
          __hip_atomic_store((ull*)(Hhi + ((nxt * BBN + gb) << 10) + 4 * j), hiq,
                             __ATOMIC_RELAXED, __HIP_MEMORY_SCOPE_AGENT);
          __hip_atomic_store((ull*)(Hlo + ((nxt * BBN + gb) << 10) + 4 * j), loq,
                             __ATOMIC_RELAXED, __HIP_MEMORY_SCOPE_AGENT);
        }
        // NO ack, NO flag: stores drain to LLC while we do X(t+1).

        const us* xh = Xhi + ((long)(t + 1) << 15) + (mrow << 9) + kj;
        const us* xl = Xlo + ((long)(t + 1) << 15) + (mrow << 9) + kj;
        bf16x8 XA[8], XB[8];
        XISS(XA, 0) XISS(XB, 1)
        __builtin_amdgcn_sched_barrier(0);
        accA = {0.f, 0.f, 0.f, 0.f};
        accB = {0.f, 0.f, 0.f, 0.f};
        accC = {0.f, 0.f, 0.f, 0.f};
        XCON(XA, 0) XISS(XA, 2)
        __builtin_amdgcn_sched_barrier(0);
        XCON(XB, 1) XISS(XB, 3)
        __builtin_amdgcn_sched_barrier(0);
        XCON(XA, 2) XCON(XB, 3)
      }
    }
  }
}

// ---------------- output GEMM: out = h_S @ W_hy + b_hy (fp32) ----------------
__global__ void out_gemm(const float* __restrict__ hfin, const float* __restrict__ Why,
                         const float* __restrict__ bhy, float* __restrict__ out) {
  int b = blockIdx.x, n = threadIdx.x;
  const float* h = hfin + (b << 10);
  float acc = 0.f;
  #pragma unroll 8
  for (int k = 0; k < HIDN; ++k) acc = fmaf(h[k], Why[(k << 9) + n], acc);
  out[(b << 9) + n] = acc + bhy[n];
}

// ---------------- launch ----------------
extern "C" void kernel_launch(void* const* d_in, const int* in_sizes, int n_in,
                              void* d_out, int out_size, void* d_ws, size_t ws_size,
                              hipStream_t stream) {
  const int*   tokens = (const int*)d_in[0];
  const float* emb    = (const float*)d_in[1];
  const float* Wxi    = (const float*)d_in[2];
  const float* Wxf    = (const float*)d_in[3];
  const float* Wxo    = (const float*)d_in[4];
  const float* Wxc    = (const float*)d_in[5];
  const float* Whi_   = (const float*)d_in[6];
  const float* Whf    = (const float*)d_in[7];
  const float* Who    = (const float*)d_in[8];
  const float* Whc    = (const float*)d_in[9];
  const float* Why    = (const float*)d_in[10];
  const float* bi     = (const float*)d_in[11];
  const float* bfv    = (const float*)d_in[12];
  const float* bo     = (const float*)d_in[13];
  const float* bc     = (const float*)d_in[14];
  const float* bhy    = (const float*)d_in[15];
  float* outp = (float*)d_out;

  char* ws = (char*)d_ws;
  size_t off = 0;
  auto carve = [&](size_t bytes) -> void* {
    void* p = ws + off;
    off += (bytes + 255) & ~(size_t)255;
    return p;
  };
  us*    Whip = (us*)carve(12582912);
  us*    Wlop = (us*)carve(12582912);
  us*    Xhi  = (us*)carve(16777216);
  us*    Xlo  = (us*)carve(16777216);
  float* hfin = (float*)carve(262144);

  // ring depth: largest power-of-two slot count (<=256) that fits.
  // K=256 -> every slot written once; no reuse, no fences, no re-sentinel.
  size_t rem = (ws_size > off) ? (ws_size - off) : 0;
  int K = 256;
  while (K > 8 && (size_t)2 * (size_t)K * 131072 + 512 > rem) K >>= 1;
  if ((size_t)2 * (size_t)K * 131072 + 512 > rem) {
    (void)hipMemsetAsync(d_out, 0, (size_t)out_size * 4, stream);  // workspace too small
    return;
  }
  us* Hhi = (us*)carve((size_t)K * 131072);
  us* Hlo = (us*)carve((size_t)K * 131072);

  // sentinel fill: 0xFF bytes = (NaN,NaN) bf16 pairs, unproducible by f2bf(tanh)
  (void)hipMemsetAsync(Hhi, 0xFF, (size_t)K * 131072, stream);
  (void)hipMemsetAsync(Hlo, 0xFF, (size_t)K * 131072, stream);

  pack_w<<<3072, 256, 0, stream>>>(Wxi, Wxf, Wxo, Wxc, Whi_, Whf, Who, Whc, Whip, Wlop);
  pack_x<<<32768, 256, 0, stream>>>(tokens, emb, Xhi, Xlo);

  (void)hipFuncSetAttribute((const void*)lstm_persist,
                            hipFuncAttributeMaxDynamicSharedMemorySize, 103424);
  lstm_persist<<<NBLK, 256, 103424, stream>>>(Whip, Wlop, Xhi, Xlo, Hhi, Hlo,
                                              hfin, bi, bfv, bo, bc, K);
  out_gemm<<<BBN, OUTN, 0, stream>>>(hfin, Why, bhy, outp);
}

// Round 5
// 3945.705 us; speedup vs baseline: 1.2149x; 1.2149x over previous
//
#include <hip/hip_runtime.h>
#include <hip/hip_bf16.h>

// ---------------- problem constants ----------------
#define EMBN   512
#define HIDN   1024
#define OUTN   512
#define BBN    64
#define SSN    256
#define NBLK   256          // blocks per step; block j owns 4 h-dims x 4 gates = 16 preact cols
#define PSTR   20           // preact LDS row stride (floats)

typedef __attribute__((ext_vector_type(8))) short bf16x8;
typedef __attribute__((ext_vector_type(4))) float f32x4;
typedef unsigned short us;
typedef unsigned long long ull;

static __device__ __forceinline__ us f2bf(float x) {
  unsigned int u = __float_as_uint(x);
  unsigned int r = (u + 0x7fffu + ((u >> 16) & 1u)) >> 16;   // RNE
  return (us)r;
}
static __device__ __forceinline__ float bf2f(us u) {
  unsigned int v = ((unsigned int)u) << 16;
  return __uint_as_float(v);
}

// ---------------- weight prepack: [j(256)][kt(48)][lane(64)][8] ----------------
// block j owns preact cols p = 16j+q, q in [0,16): gate g=q>>2, r=q&3, hd=4j+r
__global__ void pack_w(const float* __restrict__ wxi, const float* __restrict__ wxf,
                       const float* __restrict__ wxo, const float* __restrict__ wxc,
                       const float* __restrict__ whi, const float* __restrict__ whf,
                       const float* __restrict__ who, const float* __restrict__ whc,
                       us* __restrict__ Whip, us* __restrict__ Wlop) {
  int idx = blockIdx.x * 256 + threadIdx.x;       // 256*48*64 = 786432
  int lane = idx & 63;
  int kt   = (idx >> 6) % 48;
  int j    = idx / (48 * 64);
  int q = lane & 15, g = q >> 2, r = q & 3;
  int hd = 4 * j + r;
  int kb = kt * 32 + ((lane >> 4) << 3);
  const float* wx = (g == 0) ? wxi : (g == 1) ? wxf : (g == 2) ? wxo : wxc;
  const float* wh = (g == 0) ? whi : (g == 1) ? whf : (g == 2) ? who : whc;
  long obase = (long)idx * 8;
  #pragma unroll
  for (int jj = 0; jj < 8; ++jj) {
    int k = kb + jj;
    float v = (k < EMBN) ? wx[(long)k * HIDN + hd] : wh[(long)(k - EMBN) * HIDN + hd];
    us hi = f2bf(v);
    us lo = f2bf(v - bf2f(hi));
    Whip[obase + jj] = hi;
    Wlop[obase + jj] = lo;
  }
}

// ---------------- embedding gather + hi/lo split: X[t][b][k] ----------------
__global__ void pack_x(const int* __restrict__ tokens, const float* __restrict__ emb,
                       us* __restrict__ Xhi, us* __restrict__ Xlo) {
  int idx = blockIdx.x * 256 + threadIdx.x;       // 256*64*512 = 8388608
  int k = idx & 511;
  int b = (idx >> 9) & 63;
  int t = idx >> 15;
  int tok = tokens[b * SSN + t];
  float v = emb[(long)tok * EMBN + k];
  us hi = f2bf(v);
  Xhi[idx] = hi;
  Xlo[idx] = f2bf(v - bf2f(hi));
}

// chunk = 4 kt (4 hi + 4 lo frags = 8 bf16x8 = 32 VGPR)
#define XISS(A, c) { _Pragma("unroll") for (int q = 0; q < 4; ++q) { \
      A[2*q]   = *(const bf16x8*)(xh + (((c)*4 + q) << 5)); \
      A[2*q+1] = *(const bf16x8*)(xl + (((c)*4 + q) << 5)); } }
#define XCON(A, c) { _Pragma("unroll") for (int q = 0; q < 4; ++q) { \
      const int kt = (c)*4 + q; \
      bf16x8 w0 = *(const bf16x8*)(WHi + (kt << 9) + (lane << 3)); \
      bf16x8 w1 = *(const bf16x8*)(WLo + (kt << 9) + (lane << 3)); \
      accA = __builtin_amdgcn_mfma_f32_16x16x32_bf16(w0, A[2*q],   accA, 0, 0, 0); \
      accB = __builtin_amdgcn_mfma_f32_16x16x32_bf16(w0, A[2*q+1], accB, 0, 0, 0); \
      accC = __builtin_amdgcn_mfma_f32_16x16x32_bf16(w1, A[2*q],   accC, 0, 0, 0); } }
#define HISS(A, c) { _Pragma("unroll") for (int q = 0; q < 4; ++q) { \
      A[2*q]   = *(const bf16x8*)(hh + (((c)*4 + q) << 5)); \
      A[2*q+1] = *(const bf16x8*)(hl + (((c)*4 + q) << 5)); } }
#define HCON(A, c) { _Pragma("unroll") for (int q = 0; q < 4; ++q) { \
      const int kt = 16 + (c)*4 + q; \
      bf16x8 w0 = *(const bf16x8*)(WHi + (kt << 9) + (lane << 3)); \
      bf16x8 w1 = *(const bf16x8*)(WLo + (kt << 9) + (lane << 3)); \
      accA = __builtin_amdgcn_mfma_f32_16x16x32_bf16(w0, A[2*q],   accA, 0, 0, 0); \
      accB = __builtin_amdgcn_mfma_f32_16x16x32_bf16(w0, A[2*q+1], accB, 0, 0, 0); \
      accC = __builtin_amdgcn_mfma_f32_16x16x32_bf16(w1, A[2*q],   accC, 0, 0, 0); } }

// ---------------- one LSTM timestep ----------------
// 256 blocks x 256 threads (4 waves). Wave wv = batches [16wv,16wv+16).
// The stream dispatch boundary IS the barrier: h(t) written by kernel t-1 is
// visible at kernel t start (CP-managed release/acquire, cross-XCD coherent).
// Zero in-kernel waiting: plain cached loads/stores, no atomics, no flags.
// c-state lives in global cst[b][1024] (1 float per gate-thread, coalesced).
// h ping-pongs between 2 slots: step t reads slot t&1, writes slot (t+1)&1.
__launch_bounds__(256, 1)
__global__ void lstm_step(const us* __restrict__ Whip, const us* __restrict__ Wlop,
                          const us* __restrict__ Xhi, const us* __restrict__ Xlo,
                          us* __restrict__ Hhi, us* __restrict__ Hlo,
                          float* __restrict__ cst, float* __restrict__ hfin,
                          const float* __restrict__ biP, const float* __restrict__ bfP,
                          const float* __restrict__ boP, const float* __restrict__ bcP,
                          int t) {
  extern __shared__ char smem[];
  us* WHi = (us*)smem;                         // 24576 shorts
  us* WLo = WHi + 24576;                       // 24576 shorts
  float* preact = (float*)(smem + 98304);      // [64][PSTR], rows partition by wave

  const int j = blockIdx.x, tid = threadIdx.x;
  const int wv = tid >> 6, lane = tid & 63;

  // W slices -> LDS (L2-resident across launches: 3 MB/XCD, deterministic mapping)
  {
    const uint4* shi = (const uint4*)(Whip + (long)j * 24576);
    const uint4* slo = (const uint4*)(Wlop + (long)j * 24576);
    uint4* dhi = (uint4*)WHi;
    uint4* dlo = (uint4*)WLo;
    #pragma unroll
    for (int c = 0; c < 12; ++c) { int i = c * 256 + tid; dhi[i] = shi[i]; dlo[i] = slo[i]; }
  }
  const int gb = tid >> 2, gr = tid & 3;       // gate thread -> (batch, col r)
  const float bi_r = biP[4 * j + gr], bf_r = bfP[4 * j + gr];
  const float bo_r = boP[4 * j + gr], bc_r = bcP[4 * j + gr];

  const int mrow = (wv << 4) + (lane & 15);    // batch row (MFMA N-dim)
  const int kj = (lane >> 4) << 3;
  const int p0 = (lane >> 4) << 2;
  __syncthreads();                             // W in LDS ready (only barrier)

  f32x4 accA = {0.f, 0.f, 0.f, 0.f};
  f32x4 accB = {0.f, 0.f, 0.f, 0.f};
  f32x4 accC = {0.f, 0.f, 0.f, 0.f};

  // ---- X part: 4 chunks, 2-deep load/MFMA pipeline ----
  {
    const us* xh = Xhi + ((long)t << 15) + (mrow << 9) + kj;
    const us* xl = Xlo + ((long)t << 15) + (mrow << 9) + kj;
    bf16x8 XA[8], XB[8];
    XISS(XA, 0) XISS(XB, 1)
    __builtin_amdgcn_sched_barrier(0);
    XCON(XA, 0) XISS(XA, 2)
    __builtin_amdgcn_sched_barrier(0);
    XCON(XB, 1) XISS(XB, 3)
    __builtin_amdgcn_sched_barrier(0);
    XCON(XA, 2) XCON(XB, 3)
  }

  if (t > 0) {
    // ---- H part: plain cached loads (fresh by dispatch order), 4-deep pipeline ----
    const int cur = t & 1;
    const us* hh = Hhi + (((long)cur * BBN + mrow) << 10) + kj;
    const us* hl = Hlo + (((long)cur * BBN + mrow) << 10) + kj;
    bf16x8 HA[8], HB[8], HC[8], HD[8];
    HISS(HA, 0) HISS(HB, 1) HISS(HC, 2) HISS(HD, 3)
    __builtin_amdgcn_sched_barrier(0);
    HCON(HA, 0) HISS(HA, 4)
    __builtin_amdgcn_sched_barrier(0);
    HCON(HB, 1) HISS(HB, 5)
    __builtin_amdgcn_sched_barrier(0);
    HCON(HC, 2) HISS(HC, 6)
    __builtin_amdgcn_sched_barrier(0);
    HCON(HD, 3) HISS(HD, 7)
    __builtin_amdgcn_sched_barrier(0);
    HCON(HA, 4) HCON(HB, 5) HCON(HC, 6) HCON(HD, 7)
  }

  // ---- preact: lane holds D[p0+rg][mrow]; 16B LDS store (intra-wave rows) ----
  {
    f32x4 acc = accA + accB;
    acc = acc + accC;
    *(f32x4*)(preact + mrow * PSTR + p0) = acc;
  }
  // no barrier: producer lanes and consumer threads are the SAME wave.

  // ---- gates: one (b,r) per thread ----
  {
    float pi = preact[gb * PSTR + gr]      + bi_r;
    float pf = preact[gb * PSTR + 4 + gr]  + bf_r;
    float po = preact[gb * PSTR + 8 + gr]  + bo_r;
    float pc = preact[gb * PSTR + 12 + gr] + bc_r;
    float vi = 1.f / (1.f + expf(-pi));
    float vf = 1.f / (1.f + expf(-pf));
    float vo = 1.f / (1.f + expf(-po));
    float vc = tanhf(pc);
    const int ci = (gb << 10) + 4 * j + gr;
    float c_old = (t > 0) ? cst[ci] : 0.f;
    float c_new = vf * c_old + vi * vc;
    cst[ci] = c_new;
    float h = vo * tanhf(c_new);

    if (t == SSN - 1) {
      hfin[ci] = h;                            // only the final h feeds out_gemm
    } else {
      us hh_ = f2bf(h);
      us hl_ = f2bf(h - bf2f(hh_));
      // pack (hi,lo) of the 4 dims of this lane-group into two 8B quads
      unsigned int hpair = (unsigned int)hh_ | ((unsigned int)hl_ << 16);
      const int base = lane & ~3;
      unsigned int g0 = (unsigned int)__shfl((int)hpair, base);
      unsigned int g1 = (unsigned int)__shfl((int)hpair, base + 1);
      unsigned int g2 = (unsigned int)__shfl((int)hpair, base + 2);
      unsigned int g3 = (unsigned int)__shfl((int)hpair, base + 3);
      unsigned int hi01 = (g0 & 0xffffu) | (g1 << 16);
      unsigned int hi23 = (g2 & 0xffffu) | (g3 << 16);
      unsigned int lo01 = (g0 >> 16)     | (g1 & 0xffff0000u);
      unsigned int lo23 = (g2 >> 16)     | (g3 & 0xffff0000u);
      ull hiq = ((ull)hi23 << 32) | (ull)hi01;
      ull loq = ((ull)lo23 << 32) | (ull)lo01;
      const long nxt = (long)((t + 1) & 1);
      if (gr == 0) {
        *(ull*)(Hhi + ((nxt * BBN + gb) << 10) + 4 * j) = hiq;   // plain cached stores;
        *(ull*)(Hlo + ((nxt * BBN + gb) << 10) + 4 * j) = loq;   // CP release at kernel end
      }
    }
  }
}

// ---------------- output GEMM: out = h_S @ W_hy + b_hy (fp32) ----------------
__global__ void out_gemm(const float* __restrict__ hfin, const float* __restrict__ Why,
                         const float* __restrict__ bhy, float* __restrict__ out) {
  int b = blockIdx.x, n = threadIdx.x;
  const float* h = hfin + (b << 10);
  float acc = 0.f;
  #pragma unroll 8
  for (int k = 0; k < HIDN; ++k) acc = fmaf(h[k], Why[(k << 9) + n], acc);
  out[(b << 9) + n] = acc + bhy[n];
}

// ---------------- launch ----------------
extern "C" void kernel_launch(void* const* d_in, const int* in_sizes, int n_in,
                              void* d_out, int out_size, void* d_ws, size_t ws_size,
                              hipStream_t stream) {
  const int*   tokens = (const int*)d_in[0];
  const float* emb    = (const float*)d_in[1];
  const float* Wxi    = (const float*)d_in[2];
  const float* Wxf    = (const float*)d_in[3];
  const float* Wxo    = (const float*)d_in[4];
  const float* Wxc    = (const float*)d_in[5];
  const float* Whi_   = (const float*)d_in[6];
  const float* Whf    = (const float*)d_in[7];
  const float* Who    = (const float*)d_in[8];
  const float* Whc    = (const float*)d_in[9];
  const float* Why    = (const float*)d_in[10];
  const float* bi     = (const float*)d_in[11];
  const float* bfv    = (const float*)d_in[12];
  const float* bo     = (const float*)d_in[13];
  const float* bc     = (const float*)d_in[14];
  const float* bhy    = (const float*)d_in[15];
  float* outp = (float*)d_out;

  char* ws = (char*)d_ws;
  size_t off = 0;
  auto carve = [&](size_t bytes) -> void* {
    void* p = ws + off;
    off += (bytes + 255) & ~(size_t)255;
    return p;
  };
  us*    Whip = (us*)carve(12582912);
  us*    Wlop = (us*)carve(12582912);
  us*    Xhi  = (us*)carve(16777216);
  us*    Xlo  = (us*)carve(16777216);
  float* hfin = (float*)carve(262144);
  float* cst  = (float*)carve(262144);         // c-state [64][1024] fp32
  us*    Hhi  = (us*)carve(262144);            // 2 ping-pong slots [2][64][1024]
  us*    Hlo  = (us*)carve(262144);

  if (ws_size < off) {   // workspace too small: fail loudly with zero output
    (void)hipMemsetAsync(d_out, 0, (size_t)out_size * 4, stream);
    return;
  }

  pack_w<<<3072, 256, 0, stream>>>(Wxi, Wxf, Wxo, Wxc, Whi_, Whf, Who, Whc, Whip, Wlop);
  pack_x<<<32768, 256, 0, stream>>>(tokens, emb, Xhi, Xlo);

  (void)hipFuncSetAttribute((const void*)lstm_step,
                            hipFuncAttributeMaxDynamicSharedMemorySize, 103424);
  for (int t = 0; t < SSN; ++t)
    lstm_step<<<NBLK, 256, 103424, stream>>>(Whip, Wlop, Xhi, Xlo, Hhi, Hlo,
                                             cst, hfin, bi, bfv, bo, bc, t);
  out_gemm<<<BBN, OUTN, 0, stream>>>(hfin, Why, bhy, outp);
}